// Round 4
// baseline (3828.339 us; speedup 1.0000x reference)
//
#include <hip/hip_runtime.h>
#include <hip/hip_bf16.h>
#include <cstddef>

#define BATCH 16
#define TSTEPS 128
#define MSLOTS 512
#define DIN 256
#define UNITS 256
#define ZDIM 1024
#define G 8          // blocks per batch
#define NBLK (BATCH*G)
#define NTHR 512

__device__ __forceinline__ float tanhf_fast(float x) {
    float e = __expf(2.0f * x);
    return 1.0f - 2.0f / (e + 1.0f);
}
__device__ __forceinline__ float sigmoidf_fast(float x) {
    return 1.0f / (1.0f + __expf(-x));
}
__device__ __forceinline__ void st_agent(float* p, float v) {
    __hip_atomic_store(p, v, __ATOMIC_RELAXED, __HIP_MEMORY_SCOPE_AGENT);
}
__device__ __forceinline__ float ld_agent(const float* p) {
    return __hip_atomic_load(p, __ATOMIC_RELAXED, __HIP_MEMORY_SCOPE_AGENT);
}

// Flag-line barrier across the 8 blocks of one batch (one 64B line/batch).
__device__ __forceinline__ void barrier_sync(unsigned* fl, int g, unsigned tg) {
    __syncthreads();   // drains each wave's outstanding stores before flag
    if (threadIdx.x == 0)
        __hip_atomic_store(&fl[g], tg, __ATOMIC_RELEASE, __HIP_MEMORY_SCOPE_AGENT);
    if (threadIdx.x < G) {
        while (__hip_atomic_load(&fl[threadIdx.x], __ATOMIC_RELAXED,
                                 __HIP_MEMORY_SCOPE_AGENT) < tg) {}
    }
    __syncthreads();
    __builtin_amdgcn_fence(__ATOMIC_ACQUIRE, "agent");
}

// ---------------------------------------------------------------------------
// f32 GEMM + bias: C[M][N] = A @ B + bias. 64x64 tile, 256 thr, 4x4/thread.
// ---------------------------------------------------------------------------
__global__ __launch_bounds__(256) void gemm_bias_kernel(
    const float* __restrict__ A, const float* __restrict__ B,
    const float* __restrict__ bias, float* __restrict__ C,
    int M, int N, int K)
{
    __shared__ float As[16][68];
    __shared__ float Bs[16][68];
    const int tid = threadIdx.x;
    const int bm = blockIdx.x * 64;
    const int bn = blockIdx.y * 64;
    const int tx = tid & 15, ty = tid >> 4;
    const int ar = tid >> 2, ac = (tid & 3) * 4;
    const int br = tid >> 4, bc = (tid & 15) * 4;
    float acc[4][4] = {};

    for (int k0 = 0; k0 < K; k0 += 16) {
        float4 av = *(const float4*)(A + (size_t)(bm + ar) * K + k0 + ac);
        float4 bv = *(const float4*)(B + (size_t)(k0 + br) * N + bn + bc);
        As[ac + 0][ar] = av.x; As[ac + 1][ar] = av.y;
        As[ac + 2][ar] = av.z; As[ac + 3][ar] = av.w;
        *(float4*)(&Bs[br][bc]) = bv;
        __syncthreads();
#pragma unroll
        for (int kk = 0; kk < 16; ++kk) {
            float a0 = As[kk][ty*4+0], a1 = As[kk][ty*4+1];
            float a2 = As[kk][ty*4+2], a3 = As[kk][ty*4+3];
            float b0 = Bs[kk][tx*4+0], b1 = Bs[kk][tx*4+1];
            float b2 = Bs[kk][tx*4+2], b3 = Bs[kk][tx*4+3];
            acc[0][0]+=a0*b0; acc[0][1]+=a0*b1; acc[0][2]+=a0*b2; acc[0][3]+=a0*b3;
            acc[1][0]+=a1*b0; acc[1][1]+=a1*b1; acc[1][2]+=a1*b2; acc[1][3]+=a1*b3;
            acc[2][0]+=a2*b0; acc[2][1]+=a2*b1; acc[2][2]+=a2*b2; acc[2][3]+=a2*b3;
            acc[3][0]+=a3*b0; acc[3][1]+=a3*b1; acc[3][2]+=a3*b2; acc[3][3]+=a3*b3;
        }
        __syncthreads();
    }
#pragma unroll
    for (int i = 0; i < 4; ++i)
#pragma unroll
        for (int j = 0; j < 4; ++j) {
            int cn = bn + tx * 4 + j;
            C[(size_t)(bm + ty * 4 + i) * N + cn] = acc[i][j] + bias[cn];
        }
}

// ---------------------------------------------------------------------------
// query_W (f32, [k][j]) -> bf16 (round-to-nearest-even), same layout.
// ---------------------------------------------------------------------------
__global__ __launch_bounds__(256) void wq_to_bf(
    const float* __restrict__ W, unsigned short* __restrict__ O)
{
    int i = blockIdx.x * 256 + threadIdx.x;   // 256 blocks x 256 thr = 65536
    unsigned bits = __float_as_uint(W[i]);
    unsigned r = bits + 0x7fffu + ((bits >> 16) & 1u);
    O[i] = (unsigned short)(r >> 16);
}

// ---------------------------------------------------------------------------
// Persistent scan: 128 blocks (8 per batch), 512 threads, ONE barrier/step.
// Block (b,g): owns attention slots m in [g*64, g*64+64) and h-rows
// [g*32, g*32+32). Registers: AW2-slice aw2[64][2], U-slice u_r[32][2].
// LDS: keys slice (swizzled read), h/q/z routing buffers.
// Per step: redundant q (bf16 Wq from L2) -> local scores+exp -> publish
// (zc,zh,d) -> barrier -> gather -> full z -> gates -> full h,c redundant.
// ---------------------------------------------------------------------------
__global__ __launch_bounds__(NTHR, 2) void rnn_persistent(
    const float* __restrict__ attended,
    const float* __restrict__ query_b,
    const float* __restrict__ attn_W,
    const float* __restrict__ lstm_W,
    const float* __restrict__ lstm_U,
    const float* __restrict__ keys,
    const float* __restrict__ pre,
    const unsigned short* __restrict__ WqBf,
    float* zcB, float* zhB, float* dB, unsigned* flags,
    float* __restrict__ seq, float* __restrict__ hT, float* __restrict__ cT)
{
    const int bid = blockIdx.x;
    // XCD clustering heuristic (perf only): batch's 8 blocks share bid%8
    const int x = bid & 7, s = bid >> 3;
    const int b = x * 2 + (s >> 3);
    const int g = s & 7;
    const int tid = threadIdx.x;
    const int c = tid;                 // owns z-cols c and c+512

    __shared__ float big[64 * 257];    // att slice (stride 256) / keys slice (stride 257)
    __shared__ float z_s[1024];
    __shared__ float qp_s[4][256];
    __shared__ float q_s[256];
    __shared__ float h_s[256];
    __shared__ float p_s[64];
    __shared__ float aw_s[256];
    __shared__ float qb_s[256];
    __shared__ float invd_s;

    // ---- stage attended slice (contiguous 64x256) ----
    const float* attb = attended + ((size_t)b * MSLOTS + g * 64) * DIN;
    for (int i = tid * 4; i < 64 * 256; i += NTHR * 4)
        *(float4*)&big[i] = *(const float4*)&attb[i];
    if (tid < 256) { aw_s[tid] = attn_W[tid]; qb_s[tid] = query_b[tid]; h_s[tid] = 0.0f; }
    __syncthreads();

    // ---- build AW2 slice in registers: aw2[m][{c,c+512}] = sum_k att[m][k]*W2[k][col]
    float aw2[64][2];
#pragma unroll
    for (int m = 0; m < 64; ++m) { aw2[m][0] = 0.0f; aw2[m][1] = 0.0f; }
    {
        const float* W2 = lstm_W + 256 * (size_t)ZDIM;
#pragma unroll 2
        for (int k = 0; k < 256; ++k) {
            float w0 = W2[(size_t)k * ZDIM + c];
            float w1 = W2[(size_t)k * ZDIM + c + 512];
#pragma unroll
            for (int m = 0; m < 64; ++m) {
                float a = big[m * 256 + k];
                aw2[m][0] += a * w0;
                aw2[m][1] += a * w1;
            }
        }
    }
    // ---- U k-slice in registers ----
    float u_r[32][2];
#pragma unroll
    for (int k = 0; k < 32; ++k) {
        u_r[k][0] = lstm_U[(size_t)(g * 32 + k) * ZDIM + c];
        u_r[k][1] = lstm_U[(size_t)(g * 32 + k) * ZDIM + c + 512];
    }
    __syncthreads();
    // ---- stage keys slice, stride 257 (scalar stores; read-swizzle => no conflicts)
    const float* keyb = keys + ((size_t)b * MSLOTS + g * 64) * UNITS;
    for (int i = tid; i < 64 * 256; i += NTHR) {
        int m = i >> 8, j = i & 255;
        big[m * 257 + j] = keyb[i];
    }
    float c_r = 0.0f;                  // cell state for u = tid (tid<256)
    __syncthreads();

    const float* preb = pre + (size_t)b * TSTEPS * ZDIM;
    const size_t commW = ((size_t)b * G + g) * ZDIM;
    unsigned* fl = flags + b * 16;

    for (int t = 0; t < TSTEPS; ++t) {
        const int par = t & 1;
        float pre0 = preb[(size_t)t * ZDIM + c];
        float pre1 = preb[(size_t)t * ZDIM + c + 512];

        // ---- q (redundant, full): thread (j2=tid&127, kh=tid>>7), bf16 Wq from L2
        {
            const int j2 = tid & 127, kh = tid >> 7;
            const unsigned* wq = (const unsigned*)WqBf;
            float a0 = 0.0f, a1 = 0.0f;
            const int k0 = kh * 64;
#pragma unroll 8
            for (int kk = 0; kk < 64; ++kk) {
                unsigned w = wq[(size_t)(k0 + kk) * 128 + j2];
                float hk = h_s[k0 + kk];
                a0 += hk * __uint_as_float(w << 16);
                a1 += hk * __uint_as_float(w & 0xffff0000u);
            }
            qp_s[kh][j2 * 2]     = a0;
            qp_s[kh][j2 * 2 + 1] = a1;
        }
        __syncthreads();
        if (tid < 256)
            q_s[tid] = qb_s[tid] + qp_s[0][tid] + qp_s[1][tid] + qp_s[2][tid] + qp_s[3][tid];
        __syncthreads();

        // ---- scores + exp for own 64 m's (no max-subtract: |s| <= ~13)
        {
            const int m = tid >> 3, p = tid & 7;
            float sacc = 0.0f;
#pragma unroll
            for (int jj = 0; jj < 32; ++jj) {
                int j = p * 32 + ((jj + p * 4) & 31);   // rotation => 2-way banks (free)
                sacc += aw_s[j] * tanhf_fast(big[m * 257 + j] + q_s[j]);
            }
            sacc += __shfl_xor(sacc, 1);
            sacc += __shfl_xor(sacc, 2);
            sacc += __shfl_xor(sacc, 4);
            if (p == 0) p_s[m] = __expf(sacc);
        }
        __syncthreads();

        // ---- denom partial (wave 0 publishes) ----
        if (tid < 64) {
            float v = p_s[tid];
            v += __shfl_xor(v, 1);  v += __shfl_xor(v, 2);  v += __shfl_xor(v, 4);
            v += __shfl_xor(v, 8);  v += __shfl_xor(v, 16); v += __shfl_xor(v, 32);
            if (tid == 0) st_agent(&dB[par * 256 + b * 16 + g], v);
        }
        // ---- z partials from registers ----
        float zc0 = 0.0f, zc1 = 0.0f, zh0 = 0.0f, zh1 = 0.0f;
#pragma unroll
        for (int m = 0; m < 64; ++m) {
            float pm = p_s[m];
            zc0 += pm * aw2[m][0];
            zc1 += pm * aw2[m][1];
        }
#pragma unroll
        for (int k = 0; k < 32; ++k) {
            float hk = h_s[g * 32 + k];
            zh0 += hk * u_r[k][0];
            zh1 += hk * u_r[k][1];
        }
        {
            float* zc = zcB + (size_t)par * (BATCH * G * ZDIM) + commW;
            float* zh = zhB + (size_t)par * (BATCH * G * ZDIM) + commW;
            st_agent(&zc[c], zc0);        st_agent(&zc[c + 512], zc1);
            st_agent(&zh[c], zh0);        st_agent(&zh[c + 512], zh1);
        }

        barrier_sync(fl, g, (unsigned)(t + 1));     // the ONLY barrier per step

        // ---- gather z partials + denom ----
        float zcS0 = 0, zcS1 = 0, zhS0 = 0, zhS1 = 0;
        {
            const float* zc = zcB + (size_t)par * (BATCH * G * ZDIM) + (size_t)b * G * ZDIM;
            const float* zh = zhB + (size_t)par * (BATCH * G * ZDIM) + (size_t)b * G * ZDIM;
#pragma unroll
            for (int g2 = 0; g2 < G; ++g2) {
                zcS0 += ld_agent(&zc[g2 * ZDIM + c]);
                zcS1 += ld_agent(&zc[g2 * ZDIM + c + 512]);
                zhS0 += ld_agent(&zh[g2 * ZDIM + c]);
                zhS1 += ld_agent(&zh[g2 * ZDIM + c + 512]);
            }
        }
        if (tid < 8) {
            float dv = ld_agent(&dB[par * 256 + b * 16 + tid]);
            dv += __shfl_xor(dv, 1); dv += __shfl_xor(dv, 2); dv += __shfl_xor(dv, 4);
            if (tid == 0) invd_s = 1.0f / dv;
        }
        __syncthreads();
        {
            float inv = invd_s;
            z_s[c]       = pre0 + zcS0 * inv + zhS0;
            z_s[c + 512] = pre1 + zcS1 * inv + zhS1;
        }
        __syncthreads();

        // ---- gates + state (fully redundant h,c) ----
        if (tid < 256) {
            float zi = z_s[tid], zf = z_s[256 + tid], zg = z_s[512 + tid], zo = z_s[768 + tid];
            float ig = sigmoidf_fast(zi);
            float fg = sigmoidf_fast(zf);
            float gg = tanhf_fast(zg);
            float og = sigmoidf_fast(zo);
            float cn = fg * c_r + ig * gg;
            float hn = og * tanhf_fast(cn);
            c_r = cn;
            h_s[tid] = hn;
            if ((tid >> 5) == g) {                      // this block's output slice
                seq[((size_t)b * TSTEPS + t) * UNITS + tid] = hn;
                if (t == TSTEPS - 1) { hT[b * UNITS + tid] = hn; cT[b * UNITS + tid] = cn; }
            }
        }
        __syncthreads();
    }
}

// ---------------------------------------------------------------------------
extern "C" void kernel_launch(void* const* d_in, const int* in_sizes, int n_in,
                              void* d_out, int out_size, void* d_ws, size_t ws_size,
                              hipStream_t stream)
{
    (void)in_sizes; (void)n_in; (void)out_size; (void)ws_size;
    const float* inputs   = (const float*)d_in[0];
    const float* attended = (const float*)d_in[1];
    const float* key_W    = (const float*)d_in[2];
    const float* key_b    = (const float*)d_in[3];
    const float* query_W  = (const float*)d_in[4];
    const float* query_b  = (const float*)d_in[5];
    const float* attn_W   = (const float*)d_in[6];
    const float* lstm_W   = (const float*)d_in[8];
    const float* lstm_U   = (const float*)d_in[9];
    const float* lstm_b   = (const float*)d_in[10];
    // attn_b (d_in[7]) cancels in softmax — dropped.

    float* out = (float*)d_out;
    float* seq = out;
    float* hT  = out + (size_t)BATCH * TSTEPS * UNITS;
    float* cT  = hT + BATCH * UNITS;

    float* ws = (float*)d_ws;
    float* keys  = ws;                              // 8192*256      = 2,097,152
    float* pre   = keys + 2097152;                  // 2048*1024     = 2,097,152
    unsigned short* WqBf = (unsigned short*)(pre + 2097152);   // 65536 u16 = 32768 f-slots
    float* zcB   = pre + 2097152 + 32768;           // 2*16*8*1024   = 262,144
    float* zhB   = zcB + 262144;                    // 262,144
    float* dB    = zhB + 262144;                    // 2*16*16 ... 512
    unsigned* flags = (unsigned*)(dB + 512);        // 16*16 u32 = 1 KB

    hipMemsetAsync(flags, 0, BATCH * 16 * sizeof(unsigned), stream);

    // keys = attended @ key_W + key_b   (8192 x 256)
    gemm_bias_kernel<<<dim3(8192 / 64, 256 / 64), 256, 0, stream>>>(
        attended, key_W, key_b, keys, 8192, 256, 256);
    // pre = inputs @ lstm_W[:256] + lstm_b   (2048 x 1024)
    gemm_bias_kernel<<<dim3(2048 / 64, 1024 / 64), 256, 0, stream>>>(
        inputs, lstm_W, lstm_b, pre, 2048, 1024, 256);
    // Wq -> bf16
    wq_to_bf<<<dim3(256), 256, 0, stream>>>(query_W, WqBf);

    rnn_persistent<<<dim3(NBLK), dim3(NTHR), 0, stream>>>(
        attended, query_b, attn_W, lstm_W, lstm_U,
        keys, pre, WqBf, zcB, zhB, dB, flags, seq, hT, cT);
}